// Round 2
// baseline (4030.003 us; speedup 1.0000x reference)
//
#include <hip/hip_runtime.h>
#include <hip/hip_bf16.h>
#include <math.h>

#define Bn   4
#define CINn 16
#define HIDn 16
#define Tn   31
#define Hn   128
#define Wn   128
#define OCn  64
#define TAPSn 27

// Repack W[oc][cin][tap] -> Wr[q][tap][cin][16] where 16 = hdl*4+gate,
// oc = gate*16 + q*4 + hdl. Each wave (fixed q) then reads one contiguous
// 64B scalar chunk per (tap,cin). Also repack bias -> Br[q][16] at +27648.
__global__ void repack_w_kernel(const float* __restrict__ W, const float* __restrict__ b,
                                float* __restrict__ Wr) {
    int idx = blockIdx.x * blockDim.x + threadIdx.x;
    if (idx < OCn * CINn * TAPSn) {
        int j    = idx & 15;            // hdl*4+gate
        int hdl  = j >> 2;
        int gate = j & 3;
        int cin  = (idx >> 4) & 15;
        int tq   = idx >> 8;            // q*27+tap
        int tap  = tq % 27;
        int q    = tq / 27;
        int oc   = gate * 16 + q * 4 + hdl;
        Wr[idx] = W[(oc * CINn + cin) * TAPSn + tap];
    } else if (idx < OCn * CINn * TAPSn + 64) {
        int k    = idx - OCn * CINn * TAPSn;
        int j    = k & 15;
        int q    = k >> 4;
        int hdl  = j >> 2;
        int gate = j & 3;
        Wr[idx] = b[gate * 16 + q * 4 + hdl];
    }
}

__device__ __forceinline__ float sigmoidf_(float x) { return 1.f / (1.f + __expf(-x)); }
__device__ __forceinline__ float tanhf_(float x)    { return 2.f / (1.f + __expf(-2.f * x)) - 1.f; }

// Block = (b,h): 512 threads = 128 w x 4 oc-quarters. Thread owns hid
// channels 4q..4q+3 (all 4 gates) -> 16 accumulators, c[4] recurrence local.
__global__ __launch_bounds__(512, 4)
void qrnn_fused_kernel(const float* __restrict__ X, const float* __restrict__ Wr,
                       float* __restrict__ out) {
    extern __shared__ __hip_bfloat16 smem[];  // [3 slots][3 rows][16 cin][132 w]
    const int tid = threadIdx.x;
    const int w   = tid & 127;
    const int q   = __builtin_amdgcn_readfirstlane(tid >> 7);  // wave-uniform
    const int b   = blockIdx.x >> 7;
    const int h   = blockIdx.x & 127;

    const size_t strideT = (size_t)Hn * Wn;        // 16384
    const size_t strideC = (size_t)Tn * strideT;   // 507904
    const float* Xb = X + (size_t)b * CINn * strideC;

    // wave-uniform weight base: [q][tap][cin][16]
    const float* __restrict__ Wq = Wr + (size_t)q * TAPSn * CINn * 16;
    const float* __restrict__ Bq = Wr + OCn * CINn * TAPSn + q * 16;

    auto XS = [&](int slot, int r, int cin, int wi) -> __hip_bfloat16& {
        return smem[(((slot * 3 + r) * CINn + cin) * 132) + wi];
    };

    // Stage time slice u (rows h-1..h+1, all cin, w halo) into ring slot s.
    auto stage = [&](int u, int s) {
        for (int idx = tid; idx < 3 * CINn * 130; idx += 512) {
            int wi  = idx % 130;          // w = wi-1 in -1..128
            int rc  = idx / 130;
            int cin = rc & 15;
            int r   = rc >> 4;            // row h-1+r
            int hr  = h - 1 + r;
            float v = 0.f;
            if (u >= 0 && u < Tn && hr >= 0 && hr < Hn && wi >= 1 && wi <= 128)
                v = Xb[(size_t)cin * strideC + (size_t)u * strideT + (size_t)hr * Wn + (wi - 1)];
            XS(s, r, cin, wi) = __float2bfloat16(v);
        }
    };

    float c[4] = {0.f, 0.f, 0.f, 0.f};
    float bq[16];
    #pragma unroll
    for (int j = 0; j < 16; j++) bq[j] = Bq[j];

    stage(-1, 2);
    stage(0, 0);

    float* outb = out + (size_t)b * HIDn * strideC + (size_t)h * Wn + w;

    for (int t = 0; t < Tn; t++) {
        stage(t + 1, (t + 1) % 3);
        __syncthreads();

        float g[16];
        #pragma unroll
        for (int j = 0; j < 16; j++) g[j] = 0.f;

        const int s0 = (t + 2) % 3;  // slot(t-1)
        const int s1 = t % 3;        // slot(t)
        const int s2 = (t + 1) % 3;  // slot(t+1)

        #pragma unroll
        for (int kd = 0; kd < 3; kd++) {
            const int sl = (kd == 0) ? s0 : (kd == 1) ? s1 : s2;
            #pragma unroll
            for (int kh = 0; kh < 3; kh++) {
                #pragma unroll
                for (int kw = 0; kw < 3; kw++) {
                    const int tap = kd * 9 + kh * 3 + kw;
                    const float* __restrict__ wtap = Wq + (size_t)tap * CINn * 16;
                    for (int cin = 0; cin < CINn; cin++) {
                        float xv = __bfloat162float(XS(sl, kh, cin, w + kw));
                        const float* __restrict__ wrow = wtap + cin * 16; // wave-uniform -> s_load
                        #pragma unroll
                        for (int j = 0; j < 16; j++)
                            g[j] = fmaf(wrow[j], xv, g[j]);
                    }
                }
            }
        }

        // activations + recurrence + store (hd = 4q + hdl; j = hdl*4 + gate)
        #pragma unroll
        for (int hdl = 0; hdl < 4; hdl++) {
            float z = tanhf_   (g[hdl * 4 + 0] + bq[hdl * 4 + 0]);
            float f = sigmoidf_(g[hdl * 4 + 1] + bq[hdl * 4 + 1]);
            float o = sigmoidf_(g[hdl * 4 + 2] + bq[hdl * 4 + 2]);
            float i = sigmoidf_(g[hdl * 4 + 3] + bq[hdl * 4 + 3]);
            c[hdl] = f * c[hdl] + i * z;
            int hd = 4 * q + hdl;
            outb[(size_t)hd * strideC + (size_t)t * strideT] = o * c[hdl];
        }
        __syncthreads();  // protect ring slot reused by next t's stage
    }
}

extern "C" void kernel_launch(void* const* d_in, const int* in_sizes, int n_in,
                              void* d_out, int out_size, void* d_ws, size_t ws_size,
                              hipStream_t stream) {
    const float* X    = (const float*)d_in[0];
    const float* W    = (const float*)d_in[1];
    const float* bias = (const float*)d_in[2];
    float* out = (float*)d_out;
    float* Wr  = (float*)d_ws;   // 27648 + 64 floats

    repack_w_kernel<<<(OCn * CINn * TAPSn + 64 + 255) / 256, 256, 0, stream>>>(W, bias, Wr);

    const int lds_bytes = 3 * 3 * CINn * 132 * (int)sizeof(__hip_bfloat16); // 38016
    qrnn_fused_kernel<<<Bn * Hn, 512, lds_bytes, stream>>>(X, Wr, out);
}